// Round 7
// baseline (122.602 us; speedup 1.0000x reference)
//
#include <hip/hip_runtime.h>
#include <math.h>

#define BB 1024
#define TT 1024
#define HH 256
#define CC 10

// State fold: track r where h = 1 - 2r.
//   z = wd*h + win*x + bh,  m = S*z  (S = 2*log2e)
//   m = A*r + q,  A = -2*wd*S,  q = fma(x, win*S, (bh + wd)*S)
//   t = exp2(m); r' = rcp(t + 1)
//
// Round-7: de-pair the two ILP chains (pk ops coupled their trans latencies:
// pk_add waits on the LATER exp2, next pk_fma on the LATER rcp -> ~50cy
// carried path vs 38cy issue -> 45cy/step SIMD stall, phase-locked waves).
// Half-step software skew, 10-instr round-robin body: every producer ->
// consumer hop has exactly 3 intervening instrs (~12cy slack), uniformly.
//   qA=fma | uA=tA+1 | rA=rcp | mB=fma | tB=exp2 |
//   qB=fma | mA=fma  | tA=exp2| uB=tB+1| rB=rcp
// 4-buffer rolling LDS loads (zero rotation movs); separate per-row arrays
// (conflict-free staging); 8-float pad absorbs the final dead lookahead.

__global__ __launch_bounds__(HH) void vanilla_rnn_kernel(
    const float* __restrict__ x,
    const float* __restrict__ W_hx,
    const float* __restrict__ W_hh,
    const float* __restrict__ b_h,
    const float* __restrict__ W_hp,
    const float* __restrict__ b_o,
    float* __restrict__ out)
{
    __shared__ float xsA[TT + 8];   // +8 floats: lookahead/pad (reads index 1024..1031)
    __shared__ float xsB[TT + 8];
    __shared__ float part[2][CC * 4];

    const int tid = threadIdx.x;   // h index
    const int b0  = blockIdx.x * 2;

    // Stage both x rows (2 x 4 KB) into LDS: 256 threads x float4 each.
    ((float4*)xsA)[tid] = ((const float4*)(x + (size_t)b0 * TT))[tid];
    ((float4*)xsB)[tid] = ((const float4*)(x + (size_t)(b0 + 1) * TT))[tid];
    if (tid < 2) {
        ((float4*)xsA)[TT / 4 + tid] = make_float4(0.f, 0.f, 0.f, 0.f);
        ((float4*)xsB)[TT / 4 + tid] = make_float4(0.f, 0.f, 0.f, 0.f);
    }

    // Per-h constants (pre-scaled by S = 2*log2(e)) — shared by both chains.
    const float S    = 2.88539008177792681472f;
    const float winS = W_hx[tid] * S;
    const float wd   = W_hh[tid * HH + tid];
    const float Ac   = -2.0f * wd * S;
    const float bhS2 = (b_h[tid] + wd) * S;
    float whp[CC];
#pragma unroll
    for (int c = 0; c < CC; ++c) whp[c] = W_hp[c * HH + tid];

    __syncthreads();

    const float4* xa4 = (const float4*)xsA;
    const float4* xb4 = (const float4*)xsB;

    // Prologue: chain B at step -1 (rB = 0.5); chain A half-step ahead:
    // exp2 for step 0 already in flight. qBc = B's q for step 0.
    float rA = 0.5f, rB = 0.5f;
    float qBc = fmaf(xsB[0], winS, bhS2);
    float tA;
    {
        float qA0 = fmaf(xsA[0], winS, bhS2);
        float mA0 = fmaf(Ac, 0.5f, qA0);
        tA = __builtin_amdgcn_exp2f(mA0);
    }

    // One SUB completes step s of both chains and issues A's exp2 for s+1.
    // (XA1, XB1) are the x values for step s+1 (q-fma fillers).
#define SUB(XA1, XB1) {                                  \
        float qA = fmaf((XA1), winS, bhS2);              \
        float uA = tA + 1.0f;                            \
        float rAn = __builtin_amdgcn_rcpf(uA);           \
        float mB = fmaf(Ac, rB, qBc);                    \
        float tB = __builtin_amdgcn_exp2f(mB);           \
        qBc = fmaf((XB1), winS, bhS2);                   \
        float mA = fmaf(Ac, rAn, qA);                    \
        tA = __builtin_amdgcn_exp2f(mA);                 \
        float uB = tB + 1.0f;                            \
        rB = __builtin_amdgcn_rcpf(uB);                  \
        rA = rAn; }

#define SUB4(VA, VB, XA1, XB1)                           \
        SUB(VA.y, VB.y) SUB(VA.z, VB.z)                  \
        SUB(VA.w, VB.w) SUB((XA1), (XB1))

    // 4-buffer rolling loads: 16 steps/iter, loads land directly in named
    // regs (no rotation movs). Prefetch distance >= 8 steps (~350cy issue).
    // Tail (j=252): a0/a1 reload reads float4 idx 256/257 = the 8-float pad.
    float4 a0 = xa4[0], b0f = xb4[0];
    float4 a1 = xa4[1], b1f = xb4[1];
    for (int j = 0; j < TT / 4; j += 4) {
        float4 a2 = xa4[j + 2], b2f = xb4[j + 2];
        float4 a3 = xa4[j + 3], b3f = xb4[j + 3];
        SUB4(a0, b0f, a1.x, b1f.x)
        SUB4(a1, b1f, a2.x, b2f.x)
        a0 = xa4[j + 4]; b0f = xb4[j + 4];
        a1 = xa4[j + 5]; b1f = xb4[j + 5];
        SUB4(a2, b2f, a3.x, b3f.x)
        SUB4(a3, b3f, a0.x, b0f.x)
    }
#undef SUB4
#undef SUB
    // After 1024 SUBs: rA,rB hold step-1023 state; pending tA (step 1024) is dead.

    const float h0 = fmaf(-2.0f, rA, 1.0f);
    const float h1 = fmaf(-2.0f, rB, 1.0f);

    // Projection: out[b,c] = sum_h h * W_hp[c,h] + b_o[c]  (both rows)
    const int lane = tid & 63;
    const int wave = tid >> 6;
#pragma unroll
    for (int c = 0; c < CC; ++c) {
        float v0 = h0 * whp[c];
        float v1 = h1 * whp[c];
#pragma unroll
        for (int off = 32; off >= 1; off >>= 1) {
            v0 += __shfl_down(v0, off);
            v1 += __shfl_down(v1, off);
        }
        if (lane == 0) { part[0][c * 4 + wave] = v0; part[1][c * 4 + wave] = v1; }
    }
    __syncthreads();

    if (tid < 2 * CC) {
        const int bb = tid / CC;      // 0 or 1: which batch row
        const int c  = tid - bb * CC;
        float acc = b_o[c];
#pragma unroll
        for (int w = 0; w < 4; ++w) acc += part[bb][c * 4 + w];
        out[(size_t)(b0 + bb) * CC + c] = acc;
    }
}

extern "C" void kernel_launch(void* const* d_in, const int* in_sizes, int n_in,
                              void* d_out, int out_size, void* d_ws, size_t ws_size,
                              hipStream_t stream) {
    const float* x    = (const float*)d_in[0];
    const float* W_hx = (const float*)d_in[1];
    const float* W_hh = (const float*)d_in[2];
    const float* b_h  = (const float*)d_in[3];
    const float* W_hp = (const float*)d_in[4];
    const float* b_o  = (const float*)d_in[5];
    float* out = (float*)d_out;

    vanilla_rnn_kernel<<<BB / 2, HH, 0, stream>>>(x, W_hx, W_hh, b_h, W_hp, b_o, out);
}

// Round 8
// 112.387 us; speedup vs baseline: 1.0909x; 1.0909x over previous
//
#include <hip/hip_runtime.h>
#include <math.h>

#define BB 1024
#define TT 1024
#define HH 256
#define CC 10

// State fold: track r where h = 1 - 2r.
//   z = wd*h + win*x + bh,  m = S*z  (S = 2*log2e)
//   m = A*r + q,  A = -2*wd*S,  q = fma(x, win*S, (bh + wd)*S)
//   t = exp2(m); r' = rcp(t + 1)
//
// Round-8 = round-6 (best, 55.4us) + WAVE STAGGER.
// Model: wall 130 cy/step = busy 85 + stall 45, stall invariant to code
// shape because the 2 waves/SIMD run identical code from a common barrier
// -> phase-locked -> both hit exp2/rcp latency bubbles simultaneously.
// Fix: after the last __syncthreads, wave 1 runs a serial dummy rcp chain
// (~70cy, half a step) so the waves are anti-phased; each wave's latency
// bubbles overlap the other's ready issue. No barriers in the loop, so
// the offset persists. Round 7 proved intra-wave source scheduling is
// futile (compiler reorders); this skew is in TIME, not program order.

typedef float f2 __attribute__((ext_vector_type(2)));
typedef float f4 __attribute__((ext_vector_type(4)));

__global__ __launch_bounds__(HH) void vanilla_rnn_kernel(
    const float* __restrict__ x,
    const float* __restrict__ W_hx,
    const float* __restrict__ W_hh,
    const float* __restrict__ b_h,
    const float* __restrict__ W_hp,
    const float* __restrict__ b_o,
    float* __restrict__ out)
{
    __shared__ f4 xsp[TT / 2 + 2];        // interleaved pairs {A,B,A,B}; +2 f4 pad
    __shared__ float part[2][CC * 4];

    const int tid = threadIdx.x;   // h index
    const int b0  = blockIdx.x * 2;

    // Stage both rows interleaved: xsp[k] = {A(2k), B(2k), A(2k+1), B(2k+1)}.
    {
        f4 a4 = ((const f4*)(x + (size_t)b0 * TT))[tid];
        f4 b4 = ((const f4*)(x + (size_t)(b0 + 1) * TT))[tid];
        xsp[2 * tid]     = (f4){a4.x, b4.x, a4.y, b4.y};
        xsp[2 * tid + 1] = (f4){a4.z, b4.z, a4.w, b4.w};
        if (tid < 2) xsp[TT / 2 + tid] = (f4){0.f, 0.f, 0.f, 0.f};
    }

    // Per-h constants (pre-scaled by S = 2*log2(e)) — shared by both chains.
    const float S    = 2.88539008177792681472f;
    const float winS = W_hx[tid] * S;
    const float wd   = W_hh[tid * HH + tid];
    const float bhS2 = (b_h[tid] + wd) * S;
    const f2 A2   = (f2){-2.0f * wd * S, -2.0f * wd * S};
    const f2 win2 = (f2){winS, winS};
    const f2 bh2  = (f2){bhS2, bhS2};
    const f2 one2 = (f2){1.0f, 1.0f};
    float whp[CC];
#pragma unroll
    for (int c = 0; c < CC; ++c) whp[c] = W_hp[c * HH + tid];

    __syncthreads();

    // --- Wave stagger: de-phase wave 1 by ~half a recurrence step. ---
    // Serial rcp chain seeded from runtime data (not const-foldable);
    // kept live by the empty asm. ~5 x (issue+latency) ~ 60-80 cy.
    if ((tid >> 6) & 1) {
        float skew = winS;
#pragma unroll
        for (int i = 0; i < 5; ++i)
            skew = __builtin_amdgcn_rcpf(skew + 1.5f);
        asm volatile("" :: "v"(skew));
    }

    f2 r = (f2){0.5f, 0.5f};              // h0 = 0  =>  r = 0.5

#define STEP(XPAIR) {                                   \
        f2 xv = (XPAIR);                                \
        f2 q  = __builtin_elementwise_fma(xv, win2, bh2); \
        f2 m  = __builtin_elementwise_fma(A2, r, q);    \
        f2 t;                                           \
        t.x = __builtin_amdgcn_exp2f(m.x);              \
        t.y = __builtin_amdgcn_exp2f(m.y);              \
        f2 u = t + one2;                                \
        r.x = __builtin_amdgcn_rcpf(u.x);               \
        r.y = __builtin_amdgcn_rcpf(u.y); }

    // Ping-pong named registers, k += 4 (8 time-steps per iter), loads land
    // directly in va/vb/vc/vd — no rotation movs. Prefetch distance = 4
    // steps (~150 cy issue) >= LDS latency; tail loads land in the pad.
    f4 va = xsp[0], vb = xsp[1];
    for (int k = 0; k < TT / 2; k += 4) {
        f4 vc = xsp[k + 2], vd = xsp[k + 3];
        STEP(va.xy) STEP(va.zw) STEP(vb.xy) STEP(vb.zw)
        va = xsp[k + 4]; vb = xsp[k + 5];   // last iter: reads the zero pad
        STEP(vc.xy) STEP(vc.zw) STEP(vd.xy) STEP(vd.zw)
    }
#undef STEP

    const float h0 = fmaf(-2.0f, r.x, 1.0f);
    const float h1 = fmaf(-2.0f, r.y, 1.0f);

    // Projection: out[b,c] = sum_h h * W_hp[c,h] + b_o[c]  (both rows)
    const int lane = tid & 63;
    const int wave = tid >> 6;
#pragma unroll
    for (int c = 0; c < CC; ++c) {
        float v0 = h0 * whp[c];
        float v1 = h1 * whp[c];
#pragma unroll
        for (int off = 32; off >= 1; off >>= 1) {
            v0 += __shfl_down(v0, off);
            v1 += __shfl_down(v1, off);
        }
        if (lane == 0) { part[0][c * 4 + wave] = v0; part[1][c * 4 + wave] = v1; }
    }
    __syncthreads();

    if (tid < 2 * CC) {
        const int bb = tid / CC;      // 0 or 1: which batch row
        const int c  = tid - bb * CC;
        float acc = b_o[c];
#pragma unroll
        for (int w = 0; w < 4; ++w) acc += part[bb][c * 4 + w];
        out[(size_t)(b0 + bb) * CC + c] = acc;
    }
}

extern "C" void kernel_launch(void* const* d_in, const int* in_sizes, int n_in,
                              void* d_out, int out_size, void* d_ws, size_t ws_size,
                              hipStream_t stream) {
    const float* x    = (const float*)d_in[0];
    const float* W_hx = (const float*)d_in[1];
    const float* W_hh = (const float*)d_in[2];
    const float* b_h  = (const float*)d_in[3];
    const float* W_hp = (const float*)d_in[4];
    const float* b_o  = (const float*)d_in[5];
    float* out = (float*)d_out;

    vanilla_rnn_kernel<<<BB / 2, HH, 0, stream>>>(x, W_hx, W_hh, b_h, W_hp, b_o, out);
}